// Round 4
// baseline (878.703 us; speedup 1.0000x reference)
//
#include <hip/hip_runtime.h>

typedef unsigned short u16;
typedef unsigned int u32;
typedef __attribute__((ext_vector_type(8))) short bf16x8;
typedef __attribute__((ext_vector_type(4))) float f32x4;

#define NPTS 2048
#define CFEAT 256
#define NS 32
#define MTOT 262144           // 4*2048*32
#define NBLK 4096             // MTOT/64 m-tiles
#define NROW 8192             // unique gathered rows = 4*2048
#define INV_N (1.0f/262144.0f)

__device__ __forceinline__ float bf2f(u16 u) {
    union { u32 i; float f; } v; v.i = ((u32)u) << 16; return v.f;
}
__device__ __forceinline__ u16 f2bf(float f) {
    union { float f; u32 i; } v; v.f = f;
    u32 i = v.i;
    return (u16)((i + 0x7fffu + ((i >> 16) & 1u)) >> 16);
}

// async global->LDS, 16B per lane. LDS dest = wave-uniform base + lane*16; global src per-lane.
__device__ __forceinline__ void gload16(const void* g, void* l) {
    __builtin_amdgcn_global_load_lds((const __attribute__((address_space(1))) void*)g,
                                     (__attribute__((address_space(3))) void*)l, 16, 0, 0);
}

// ---------------- prep: pack W1 -> [feat(256) | xyz(3) | 0(29)] (K=288), W2 (K=256), bf16 ----------------
__global__ __launch_bounds__(256) void prep_k(const float* __restrict__ W1, const float* __restrict__ W2,
                                              u16* __restrict__ Wp1, u16* __restrict__ Wp2) {
    int o = blockIdx.x, t = threadIdx.x;
    Wp1[o * 288 + t] = f2bf(W1[o * 259 + 3 + t]);
    if (t < 32) Wp1[o * 288 + 256 + t] = (t < 3) ? f2bf(W1[o * 259 + t]) : (u16)0;
    Wp2[o * 256 + t] = f2bf(W2[o * 256 + t]);
}

// ---------------- cylinder query: wave per point, ballot compaction ----------------
__global__ __launch_bounds__(256) void query_k(const float* __restrict__ xyz, const float* __restrict__ rot,
                                               int* __restrict__ idx) {
    int pid = blockIdx.x * 4 + (threadIdx.x >> 6);
    int lane = threadIdx.x & 63;
    int b = pid >> 11, p = pid & 2047;
    const float* xb = xyz + (size_t)b * NPTS * 3;
    float px = xb[p * 3 + 0], py = xb[p * 3 + 1], pz = xb[p * 3 + 2];
    const float* rp = rot + (size_t)pid * 9;
    float r00 = rp[0], r01 = rp[1], r02 = rp[2];
    float r10 = rp[3], r11 = rp[4], r12 = rp[5];
    float r20 = rp[6], r21 = rp[7], r22 = rp[8];
    int cnt = 0, first = 0;
    for (int n0 = 0; n0 < NPTS && cnt < NS; n0 += 64) {
        int n = n0 + lane;
        float dx = __fsub_rn(xb[n * 3 + 0], px);
        float dy = __fsub_rn(xb[n * 3 + 1], py);
        float dz = __fsub_rn(xb[n * 3 + 2], pz);
        float a0 = __fadd_rn(__fadd_rn(__fmul_rn(r00, dx), __fmul_rn(r01, dy)), __fmul_rn(r02, dz));
        float a1 = __fadd_rn(__fadd_rn(__fmul_rn(r10, dx), __fmul_rn(r11, dy)), __fmul_rn(r12, dz));
        float a2 = __fadd_rn(__fadd_rn(__fmul_rn(r20, dx), __fmul_rn(r21, dy)), __fmul_rn(r22, dz));
        float t2 = __fadd_rn(__fmul_rn(a1, a1), __fmul_rn(a2, a2));
        bool valid = (t2 < 0.0025f) && (a0 > -0.02f) && (a0 < 0.04f);
        unsigned long long bal = __ballot(valid);
        if (cnt == 0 && bal) first = n0 + __builtin_ctzll(bal);
        int rank = __builtin_popcountll(bal & ((1ull << lane) - 1ull));
        int slot = cnt + rank;
        if (valid && slot < NS) idx[(size_t)pid * NS + slot] = n;
        cnt += __builtin_popcountll(bal);
    }
    int filled = cnt < NS ? cnt : NS;
    if (lane >= filled && lane < NS) idx[(size_t)pid * NS + lane] = (cnt > 0) ? first : 0;
}

// ---------------- features (B,C,N) fp32 -> featT (B,N,C) bf16 ----------------
__global__ __launch_bounds__(256) void featT_k(const float* __restrict__ feat, u16* __restrict__ featT) {
    __shared__ float sm[32 * 33];
    int b = blockIdx.z;
    int n0 = blockIdx.x * 32, c0 = blockIdx.y * 32;
    int t = threadIdx.x, x = t & 31, y = t >> 5;
    #pragma unroll
    for (int rr = 0; rr < 4; rr++) {
        int c = c0 + y + rr * 8;
        sm[(y + rr * 8) * 33 + x] = feat[((size_t)(b * CFEAT + c)) * NPTS + n0 + x];
    }
    __syncthreads();
    #pragma unroll
    for (int rr = 0; rr < 4; rr++) {
        int n = n0 + y + rr * 8;
        featT[((size_t)(b * NPTS + n)) * CFEAT + c0 + x] = f2bf(sm[x * 33 + (y + rr * 8)]);
    }
}

// ---------------- gxyz: rotated, scaled neighbor offsets, (MTOT,4) bf16 ----------------
__global__ __launch_bounds__(256) void gxyz_k(const float* __restrict__ xyz, const float* __restrict__ rot,
                                              const int* __restrict__ idx, u16* __restrict__ gxyz) {
    int m = blockIdx.x * 256 + threadIdx.x;
    int pid = m >> 5;
    int b = pid >> 11, p = pid & 2047;
    int i = idx[m];
    const float* xb = xyz + (size_t)b * NPTS * 3;
    float dx = (xb[i * 3 + 0] - xb[p * 3 + 0]) * 20.0f;
    float dy = (xb[i * 3 + 1] - xb[p * 3 + 1]) * 20.0f;
    float dz = (xb[i * 3 + 2] - xb[p * 3 + 2]) * 20.0f;
    const float* rp = rot + (size_t)pid * 9;
    float g0 = dx * rp[0] + dy * rp[3] + dz * rp[6];
    float g1 = dx * rp[1] + dy * rp[4] + dz * rp[7];
    float g2 = dx * rp[2] + dy * rp[5] + dz * rp[8];
    uint2 v;
    v.x = (u32)f2bf(g0) | ((u32)f2bf(g1) << 16);
    v.y = (u32)f2bf(g2);
    *(uint2*)(gxyz + (size_t)m * 4) = v;
}

// ---------------- zero scratch ----------------
__global__ __launch_bounds__(256) void zero_k(float* __restrict__ p, int n) {
    int i = blockIdx.x * 256 + threadIdx.x;
    if (i < n) p[i] = 0.f;
}

// ---------------- histogram via LDS accumulation: one block per batch, NO global atomics ----------------
// cnt_r, X_r = sum of gxyz over occurrences of row r; xstat partials per block (summed in ab1_k)
__global__ __launch_bounds__(256) void count2_k(const int* __restrict__ idx, const u16* __restrict__ gxyz,
                                                float* __restrict__ cntx, float* __restrict__ xst4) {
    __shared__ float hist[2048 * 4];   // 32 KB
    __shared__ float red[9 * 4];
    const int t = threadIdx.x, lane = t & 63, wave = t >> 6;
    const int b = blockIdx.x;          // batch
    for (int i = t; i < 8192; i += 256) hist[i] = 0.f;
    __syncthreads();
    float p[9] = {0.f,0.f,0.f,0.f,0.f,0.f,0.f,0.f,0.f};
    const int base = b * 65536;
    #pragma unroll 4
    for (int u = 0; u < 256; u++) {
        int m = base + u * 256 + t;
        int r = idx[m];                // local row 0..2047
        uint2 v = *(const uint2*)(gxyz + (size_t)m * 4);
        float x0 = bf2f((u16)(v.x & 0xffff));
        float x1 = bf2f((u16)(v.x >> 16));
        float x2 = bf2f((u16)(v.y & 0xffff));
        atomicAdd(hist + r * 4 + 0, 1.f);   // LDS atomics (ds_add_f32)
        atomicAdd(hist + r * 4 + 1, x0);
        atomicAdd(hist + r * 4 + 2, x1);
        atomicAdd(hist + r * 4 + 3, x2);
        p[0] += x0; p[1] += x1; p[2] += x2;
        p[3] += x0 * x0; p[4] += x0 * x1; p[5] += x0 * x2;
        p[6] += x1 * x1; p[7] += x1 * x2; p[8] += x2 * x2;
    }
    __syncthreads();
    for (int i = t; i < 8192; i += 256) cntx[b * 8192 + i] = hist[i];   // plain coalesced flush
    #pragma unroll
    for (int k = 0; k < 9; k++) {
        float s = p[k];
        #pragma unroll
        for (int o = 1; o < 64; o <<= 1) s += __shfl_xor(s, o);
        if (lane == 0) red[k * 4 + wave] = s;
    }
    __syncthreads();
    if (t < 9) xst4[b * 9 + t] = red[t * 4 + 0] + red[t * 4 + 1] + red[t * 4 + 2] + red[t * 4 + 3];
}

// ---------------- z-GEMM over the 8192 unique rows + fused weighted stats1 reduction ----------------
__global__ __launch_bounds__(256) void zgemm_k(const u16* __restrict__ featT, const u16* __restrict__ Wp1,
                                               const float* __restrict__ cntx,
                                               float* __restrict__ Sacc, float* __restrict__ Qacc,
                                               float* __restrict__ Xacc) {
    __shared__ __attribute__((aligned(16))) u16 As[64 * 32];
    __shared__ __attribute__((aligned(16))) u16 Bs[256 * 32];
    const int tid = threadIdx.x;
    const int lane = tid & 63, wave = tid >> 6;
    const int quad = lane >> 4, tl = lane & 15;
    const int m0 = blockIdx.x * 64;
    const int srow = tid >> 2, sc16 = tid & 3;
    const int abase = (m0 + srow) * CFEAT + sc16 * 8;

    f32x4 acc[4][4];
    #pragma unroll
    for (int i = 0; i < 4; i++)
        #pragma unroll
        for (int j = 0; j < 4; j++) acc[i][j] = (f32x4){0.f, 0.f, 0.f, 0.f};

    for (int ks = 0; ks < 8; ks++) {
        const int k0 = ks * 32;
        __syncthreads();
        gload16(featT + abase + k0, As + tid * 8);
        #pragma unroll
        for (int q = 0; q < 4; q++)
            gload16(Wp1 + (srow + q * 64) * 288 + k0 + sc16 * 8, Bs + q * 2048 + tid * 8);
        __syncthreads();
        bf16x8 af[4], bv[4];
        #pragma unroll
        for (int i = 0; i < 4; i++) af[i] = *(const bf16x8*)(As + (i * 16 + tl) * 32 + quad * 8);
        #pragma unroll
        for (int j = 0; j < 4; j++) bv[j] = *(const bf16x8*)(Bs + (wave * 64 + j * 16 + tl) * 32 + quad * 8);
        #pragma unroll
        for (int i = 0; i < 4; i++)
            #pragma unroll
            for (int j = 0; j < 4; j++)
                acc[i][j] = __builtin_amdgcn_mfma_f32_16x16x32_bf16(af[i], bv[j], acc[i][j], 0, 0, 0);
    }

    #pragma unroll
    for (int j = 0; j < 4; j++) {
        int col = wave * 64 + j * 16 + tl;
        float wx0 = bf2f(Wp1[col * 288 + 256]);
        float wx1 = bf2f(Wp1[col * 288 + 257]);
        float wx2 = bf2f(Wp1[col * 288 + 258]);
        float S = 0.f, Q = 0.f, X = 0.f;
        #pragma unroll
        for (int i = 0; i < 4; i++)
            #pragma unroll
            for (int rr = 0; rr < 4; rr++) {
                int row = i * 16 + quad * 4 + rr;
                float4 cx = *(const float4*)(cntx + (size_t)(m0 + row) * 4);
                float z = acc[i][j][rr];
                S += cx.x * z;
                Q += cx.x * z * z;
                X += z * (wx0 * cx.y + wx1 * cx.z + wx2 * cx.w);
            }
        S += __shfl_xor(S, 16); S += __shfl_xor(S, 32);
        Q += __shfl_xor(Q, 16); Q += __shfl_xor(Q, 32);
        X += __shfl_xor(X, 16); X += __shfl_xor(X, 32);
        if (quad == 0) {
            atomicAdd(Sacc + col, S);
            atomicAdd(Qacc + col, Q);
            atomicAdd(Xacc + col, X);
        }
    }
}

// ---------------- assemble stats1 -> (a,b) affine ----------------
__global__ __launch_bounds__(256) void ab1_k(const float* __restrict__ Sacc, const float* __restrict__ Qacc,
                                             const float* __restrict__ Xacc, const float* __restrict__ xst4,
                                             const u16* __restrict__ Wp1,
                                             const float* __restrict__ gamma, const float* __restrict__ beta,
                                             float* __restrict__ ab) {
    int c = threadIdx.x;
    float xs[9];
    #pragma unroll
    for (int k = 0; k < 9; k++) xs[k] = xst4[k] + xst4[9 + k] + xst4[18 + k] + xst4[27 + k];
    float wx0 = bf2f(Wp1[c * 288 + 256]);
    float wx1 = bf2f(Wp1[c * 288 + 257]);
    float wx2 = bf2f(Wp1[c * 288 + 258]);
    float S = Sacc[c] + wx0 * xs[0] + wx1 * xs[1] + wx2 * xs[2];
    float qxx = wx0 * wx0 * xs[3] + wx1 * wx1 * xs[6] + wx2 * wx2 * xs[8]
              + 2.f * (wx0 * wx1 * xs[4] + wx0 * wx2 * xs[5] + wx1 * wx2 * xs[7]);
    float Q = Qacc[c] + 2.f * Xacc[c] + qxx;
    float mu = S * INV_N;
    float var = Q * INV_N - mu * mu;
    float a = gamma[c] * rsqrtf(var + 1e-5f);
    ab[c] = a;
    ab[256 + c] = beta[c] - mu * a;
}

// ---------------- single fused pass: GEMM1 -> norm1+relu (per-wave slices) -> GEMM2 -> stats2 + max/min --
// LDS: As[2] (4KB each) + Bs[2] (16KB each) + rowbase = 40.3 KB -> 3 blocks/CU target.
// GEMM2's A operand (y1 slice, 64x32) lives in the As double buffer: slice t is produced entirely by
// wave t>>1 from its GEMM1 accumulator (cols wave*64 + j*16 + tl), written with norm1+relu applied.
__global__ __launch_bounds__(256) void full_k(
    const u16* __restrict__ featT, const u16* __restrict__ gxyz, const int* __restrict__ idx,
    const u16* __restrict__ Wp1, const u16* __restrict__ Wp2, const float* __restrict__ ab1,
    float* __restrict__ psum, float* __restrict__ psq,
    float* __restrict__ ymax, float* __restrict__ ymin)
{
    __shared__ __attribute__((aligned(16))) u16 As[2][64 * 32];   //  8 KB
    __shared__ __attribute__((aligned(16))) u16 Bs[2][256 * 32];  // 32 KB
    __shared__ int rowbase_s[64];

    const int tid = threadIdx.x;
    const int lane = tid & 63, wave = tid >> 6;
    const int quad = lane >> 4, tl = lane & 15;
    const int bx = blockIdx.x;
    const int m0 = bx * 64;

    if (tid < 64) {
        int m = m0 + tid;
        int gi = idx[m];
        int b = m >> 16;
        rowbase_s[tid] = (b * NPTS + gi) * CFEAT;
    }
    __syncthreads();
    const int srow = tid >> 2, sc16 = tid & 3;
    const int abase = rowbase_s[srow] + sc16 * 8;

    auto mfma_tile = [&](f32x4 (&ac)[4][4], const u16* a_lds, const u16* b_lds) {
        bf16x8 af[4], bv[4];
        #pragma unroll
        for (int i = 0; i < 4; i++) af[i] = *(const bf16x8*)(a_lds + (i * 16 + tl) * 32 + quad * 8);
        #pragma unroll
        for (int j = 0; j < 4; j++) bv[j] = *(const bf16x8*)(b_lds + (wave * 64 + j * 16 + tl) * 32 + quad * 8);
        #pragma unroll
        for (int i = 0; i < 4; i++)
            #pragma unroll
            for (int j = 0; j < 4; j++)
                ac[i][j] = __builtin_amdgcn_mfma_f32_16x16x32_bf16(af[i], bv[j], ac[i][j], 0, 0, 0);
    };

    auto stage1 = [&](int t, int buf) {
        if (t < 8) {
            gload16(featT + abase + t * 32, &As[buf][tid * 8]);
            #pragma unroll
            for (int q = 0; q < 4; q++)
                gload16(Wp1 + (srow + q * 64) * 288 + t * 32 + sc16 * 8, &Bs[buf][q * 2048 + tid * 8]);
        } else {  // xyz tile: sparse A written from VGPR, B cols 256..287
            uint4 va = make_uint4(0, 0, 0, 0);
            if (sc16 == 0) {
                uint2 g2 = *(const uint2*)(gxyz + (size_t)(m0 + srow) * 4);
                va.x = g2.x; va.y = g2.y;
            }
            *(uint4*)(&As[buf][srow * 32 + sc16 * 8]) = va;
            #pragma unroll
            for (int q = 0; q < 4; q++)
                gload16(Wp1 + (srow + q * 64) * 288 + 256 + sc16 * 8, &Bs[buf][q * 2048 + tid * 8]);
        }
    };

    f32x4 acc[4][4];
    #pragma unroll
    for (int i = 0; i < 4; i++)
        #pragma unroll
        for (int j = 0; j < 4; j++) acc[i][j] = (f32x4){0.f, 0.f, 0.f, 0.f};

    // ---- GEMM1: 9 K-tiles (8 feat + 1 xyz), 2-phase pipeline ----
    stage1(0, 0);
    __syncthreads();
    for (int t = 0; t < 9; t++) {
        const int cur = t & 1;
        if (t < 8) stage1(t + 1, cur ^ 1);     // prefetch overlaps with compute below
        mfma_tile(acc, &As[cur][0], &Bs[cur][0]);
        __syncthreads();                        // drains vmcnt(0): prefetch landed
    }

    // per-wave norm1 coefficients for this wave's 64 cols (4 j-groups)
    float a_s[4], b_s[4];
    #pragma unroll
    for (int j = 0; j < 4; j++) {
        int col = wave * 64 + j * 16 + tl;
        a_s[j] = ab1[col];
        b_s[j] = ab1[256 + col];
    }

    // producer wave (t>>1) writes y1 slice t (norm1+relu, bf16) into an As buffer
    auto write_slice = [&](int t, u16* dst) {
        const int j0 = (t & 1) * 2;
        #pragma unroll
        for (int jj = 0; jj < 2; jj++) {
            float a = a_s[j0 + jj], bb = b_s[j0 + jj];
            #pragma unroll
            for (int i = 0; i < 4; i++)
                #pragma unroll
                for (int r = 0; r < 4; r++) {
                    float v = fmaxf(fmaf(acc[i][j0 + jj][r], a, bb), 0.f);
                    dst[(i * 16 + quad * 4 + r) * 32 + jj * 16 + tl] = f2bf(v);
                }
        }
    };

    // ---- GEMM2: 8 K-steps; A = y1 slices in As dbuf, B = Wp2 tiles in Bs dbuf ----
    f32x4 acc2[4][4];
    #pragma unroll
    for (int i = 0; i < 4; i++)
        #pragma unroll
        for (int j = 0; j < 4; j++) acc2[i][j] = (f32x4){0.f, 0.f, 0.f, 0.f};

    // prologue: slice 0 + Wp2 tile 0 into buffer 0 (after GEMM1's final barrier)
    #pragma unroll
    for (int q = 0; q < 4; q++)
        gload16(Wp2 + (srow + q * 64) * 256 + sc16 * 8, &Bs[0][q * 2048 + tid * 8]);
    if (wave == 0) write_slice(0, &As[0][0]);
    __syncthreads();

    for (int t = 0; t < 8; t++) {
        const int cur = t & 1;
        if (t < 7) {
            #pragma unroll
            for (int q = 0; q < 4; q++)
                gload16(Wp2 + (srow + q * 64) * 256 + (t + 1) * 32 + sc16 * 8, &Bs[cur ^ 1][q * 2048 + tid * 8]);
            if (wave == ((t + 1) >> 1)) write_slice(t + 1, &As[cur ^ 1][0]);
        }
        mfma_tile(acc2, &As[cur][0], &Bs[cur][0]);
        __syncthreads();
    }

    // ---- epilogue: stats2 + per-point max/min ----
    #pragma unroll
    for (int j = 0; j < 4; j++) {
        int col = wave * 64 + j * 16 + tl;
        float s = 0.f, q2 = 0.f;
        float mx0 = -3.0e38f, mn0 = 3.0e38f, mx1 = -3.0e38f, mn1 = 3.0e38f;
        #pragma unroll
        for (int i = 0; i < 4; i++)
            #pragma unroll
            for (int r = 0; r < 4; r++) {
                float v = acc2[i][j][r];
                s += v; q2 += v * v;
                if (i < 2) { mx0 = fmaxf(mx0, v); mn0 = fminf(mn0, v); }
                else       { mx1 = fmaxf(mx1, v); mn1 = fminf(mn1, v); }
            }
        s += __shfl_xor(s, 16); s += __shfl_xor(s, 32);
        q2 += __shfl_xor(q2, 16); q2 += __shfl_xor(q2, 32);
        mx0 = fmaxf(mx0, __shfl_xor(mx0, 16)); mx0 = fmaxf(mx0, __shfl_xor(mx0, 32));
        mn0 = fminf(mn0, __shfl_xor(mn0, 16)); mn0 = fminf(mn0, __shfl_xor(mn0, 32));
        mx1 = fmaxf(mx1, __shfl_xor(mx1, 16)); mx1 = fmaxf(mx1, __shfl_xor(mx1, 32));
        mn1 = fminf(mn1, __shfl_xor(mn1, 16)); mn1 = fminf(mn1, __shfl_xor(mn1, 32));
        if (quad == 0) {
            psum[(size_t)bx * 256 + col] = s;
            psq[(size_t)bx * 256 + col] = q2;
            size_t p0 = (size_t)(bx * 2) * 256 + col;
            size_t p1 = (size_t)(bx * 2 + 1) * 256 + col;
            ymax[p0] = mx0; ymin[p0] = mn0;
            ymax[p1] = mx1; ymin[p1] = mn1;
        }
    }
}

// ---------------- fallback (small-ws, round-2 proven): recompute GEMM1 in pass 2 ----------------
template <int FULL>
__global__ __launch_bounds__(256) void fused_k(
    const u16* __restrict__ featT, const u16* __restrict__ gxyz, const int* __restrict__ idx,
    const u16* __restrict__ Wp1, const u16* __restrict__ Wp2, const float* __restrict__ ab1,
    float* __restrict__ psum, float* __restrict__ psq,
    float* __restrict__ ymax, float* __restrict__ ymin)
{
    __shared__ __attribute__((aligned(16))) u16 As[64 * 32];
    __shared__ __attribute__((aligned(16))) u16 Bs[256 * 32];
    __shared__ __attribute__((aligned(16))) u16 y1s[FULL ? 64 * 264 : 16];
    __shared__ int rowbase_s[64];

    const int tid = threadIdx.x;
    const int lane = tid & 63, wave = tid >> 6;
    const int quad = lane >> 4, tl = lane & 15;
    const int bx = blockIdx.x;
    const int m0 = bx * 64;

    if (tid < 64) {
        int m = m0 + tid;
        int gi = idx[m];
        int b = m >> 16;
        rowbase_s[tid] = (b * NPTS + gi) * CFEAT;
    }
    __syncthreads();
    const int srow = tid >> 2, sc16 = tid & 3;
    const int abase = rowbase_s[srow] + sc16 * 8;

    f32x4 acc[4][4];
    #pragma unroll
    for (int i = 0; i < 4; i++)
        #pragma unroll
        for (int j = 0; j < 4; j++) acc[i][j] = (f32x4){0.f, 0.f, 0.f, 0.f};

    auto mfma_tile = [&](f32x4 (&ac)[4][4], const u16* a_lds, int a_stride) {
        bf16x8 af[4], bv[4];
        #pragma unroll
        for (int i = 0; i < 4; i++) af[i] = *(const bf16x8*)(a_lds + (i * 16 + tl) * a_stride + quad * 8);
        #pragma unroll
        for (int j = 0; j < 4; j++) bv[j] = *(const bf16x8*)(Bs + (wave * 64 + j * 16 + tl) * 32 + quad * 8);
        #pragma unroll
        for (int i = 0; i < 4; i++)
            #pragma unroll
            for (int j = 0; j < 4; j++)
                ac[i][j] = __builtin_amdgcn_mfma_f32_16x16x32_bf16(af[i], bv[j], ac[i][j], 0, 0, 0);
    };

    for (int ks = 0; ks < 8; ks++) {
        const int k0 = ks * 32;
        __syncthreads();
        gload16(featT + abase + k0, As + tid * 8);
        #pragma unroll
        for (int q = 0; q < 4; q++)
            gload16(Wp1 + (srow + q * 64) * 288 + k0 + sc16 * 8, Bs + q * 2048 + tid * 8);
        __syncthreads();
        mfma_tile(acc, As, 32);
    }
    {
        __syncthreads();
        uint4 va = make_uint4(0, 0, 0, 0);
        if (sc16 == 0) {
            uint2 g2 = *(const uint2*)(gxyz + (size_t)(m0 + srow) * 4);
            va.x = g2.x; va.y = g2.y;
        }
        *(uint4*)(As + srow * 32 + sc16 * 8) = va;
        #pragma unroll
        for (int q = 0; q < 4; q++)
            gload16(Wp1 + (srow + q * 64) * 288 + 256 + sc16 * 8, Bs + q * 2048 + tid * 8);
        __syncthreads();
        mfma_tile(acc, As, 32);
    }

    if (!FULL) {
        #pragma unroll
        for (int j = 0; j < 4; j++) {
            float s = 0.f, q2 = 0.f;
            #pragma unroll
            for (int i = 0; i < 4; i++) {
                s += acc[i][j][0] + acc[i][j][1] + acc[i][j][2] + acc[i][j][3];
                q2 += acc[i][j][0]*acc[i][j][0] + acc[i][j][1]*acc[i][j][1]
                    + acc[i][j][2]*acc[i][j][2] + acc[i][j][3]*acc[i][j][3];
            }
            s += __shfl_xor(s, 16); s += __shfl_xor(s, 32);
            q2 += __shfl_xor(q2, 16); q2 += __shfl_xor(q2, 32);
            if (quad == 0) {
                int col = wave * 64 + j * 16 + tl;
                psum[(size_t)bx * 256 + col] = s;
                psq[(size_t)bx * 256 + col] = q2;
            }
        }
        return;
    }

    #pragma unroll
    for (int j = 0; j < 4; j++) {
        int col = wave * 64 + j * 16 + tl;
        float a = ab1[col], bb = ab1[256 + col];
        #pragma unroll
        for (int i = 0; i < 4; i++)
            #pragma unroll
            for (int r = 0; r < 4; r++) {
                float v = fmaxf(fmaf(acc[i][j][r], a, bb), 0.f);
                y1s[(i * 16 + quad * 4 + r) * 264 + col] = f2bf(v);
            }
    }

    f32x4 acc2[4][4];
    #pragma unroll
    for (int i = 0; i < 4; i++)
        #pragma unroll
        for (int j = 0; j < 4; j++) acc2[i][j] = (f32x4){0.f, 0.f, 0.f, 0.f};
    for (int ks = 0; ks < 8; ks++) {
        const int k0 = ks * 32;
        __syncthreads();
        #pragma unroll
        for (int q = 0; q < 4; q++)
            gload16(Wp2 + (srow + q * 64) * 256 + k0 + sc16 * 8, Bs + q * 2048 + tid * 8);
        __syncthreads();
        mfma_tile(acc2, y1s + k0, 264);
    }

    #pragma unroll
    for (int j = 0; j < 4; j++) {
        int col = wave * 64 + j * 16 + tl;
        float s = 0.f, q2 = 0.f;
        float mx0 = -3.0e38f, mn0 = 3.0e38f, mx1 = -3.0e38f, mn1 = 3.0e38f;
        #pragma unroll
        for (int i = 0; i < 4; i++)
            #pragma unroll
            for (int r = 0; r < 4; r++) {
                float v = acc2[i][j][r];
                s += v; q2 += v * v;
                if (i < 2) { mx0 = fmaxf(mx0, v); mn0 = fminf(mn0, v); }
                else       { mx1 = fmaxf(mx1, v); mn1 = fminf(mn1, v); }
            }
        s += __shfl_xor(s, 16); s += __shfl_xor(s, 32);
        q2 += __shfl_xor(q2, 16); q2 += __shfl_xor(q2, 32);
        mx0 = fmaxf(mx0, __shfl_xor(mx0, 16)); mx0 = fmaxf(mx0, __shfl_xor(mx0, 32));
        mn0 = fminf(mn0, __shfl_xor(mn0, 16)); mn0 = fminf(mn0, __shfl_xor(mn0, 32));
        mx1 = fmaxf(mx1, __shfl_xor(mx1, 16)); mx1 = fmaxf(mx1, __shfl_xor(mx1, 32));
        mn1 = fminf(mn1, __shfl_xor(mn1, 16)); mn1 = fminf(mn1, __shfl_xor(mn1, 32));
        if (quad == 0) {
            psum[(size_t)bx * 256 + col] = s;
            psq[(size_t)bx * 256 + col] = q2;
            size_t p0 = (size_t)(bx * 2) * 256 + col;
            size_t p1 = (size_t)(bx * 2 + 1) * 256 + col;
            ymax[p0] = mx0; ymin[p0] = mn0;
            ymax[p1] = mx1; ymin[p1] = mn1;
        }
    }
}

// ---------------- stats reduction: 64 blocks x 64 rows (coalesced), then 1-block finish ----------------
__global__ __launch_bounds__(256) void reduce1_k(const float* __restrict__ psum, const float* __restrict__ psq,
                                                 float* __restrict__ ps2, float* __restrict__ pq2) {
    int j = blockIdx.x, t = threadIdx.x;
    float s = 0.f, q = 0.f;
    #pragma unroll 4
    for (int kk = 0; kk < 64; kk++) {
        size_t r = (size_t)(j * 64 + kk) * 256 + t;
        s += psum[r]; q += psq[r];
    }
    ps2[j * 256 + t] = s;
    pq2[j * 256 + t] = q;
}

__global__ __launch_bounds__(256) void reduce2_k(const float* __restrict__ ps2, const float* __restrict__ pq2,
                                                 const float* __restrict__ gamma, const float* __restrict__ beta,
                                                 float* __restrict__ ab) {
    int c = threadIdx.x;
    float S = 0.f, Q = 0.f;
    for (int j = 0; j < 64; j++) {
        S += ps2[j * 256 + c];
        Q += pq2[j * 256 + c];
    }
    float mu = S * INV_N;
    float var = Q * INV_N - mu * mu;
    float a = gamma[c] * rsqrtf(var + 1e-5f);
    ab[c] = a;
    ab[256 + c] = beta[c] - mu * a;
}

// ---------------- final: relu(a*(a>=0?max:min)+b), transpose -> (B,O,N) ----------------
__global__ __launch_bounds__(256) void final_k(const float* __restrict__ ymax, const float* __restrict__ ymin,
                                               const float* __restrict__ ab, float* __restrict__ out) {
    __shared__ float sm[32 * 33];
    int b = blockIdx.z;
    int n0 = blockIdx.x * 32, o0 = blockIdx.y * 32;
    int t = threadIdx.x, x = t & 31, y = t >> 5;
    #pragma unroll
    for (int rr = 0; rr < 4; rr++) {
        int n = n0 + y + rr * 8;
        int o = o0 + x;
        float a = ab[o], bb = ab[256 + o];
        size_t p = (size_t)(b * NPTS + n) * 256 + o;
        float v = (a >= 0.f) ? ymax[p] : ymin[p];
        sm[(y + rr * 8) * 33 + x] = fmaxf(fmaf(v, a, bb), 0.f);
    }
    __syncthreads();
    #pragma unroll
    for (int rr = 0; rr < 4; rr++)
        out[((size_t)(b * 256 + o0 + y + rr * 8)) * NPTS + n0 + x] = sm[x * 33 + (y + rr * 8)];
}

extern "C" void kernel_launch(void* const* d_in, const int* in_sizes, int n_in,
                              void* d_out, int out_size, void* d_ws, size_t ws_size,
                              hipStream_t stream) {
    const float* xyz    = (const float*)d_in[0];
    const float* feat   = (const float*)d_in[1];
    const float* rot    = (const float*)d_in[2];
    const float* W1     = (const float*)d_in[3];
    const float* gamma1 = (const float*)d_in[4];
    const float* beta1  = (const float*)d_in[5];
    const float* W2     = (const float*)d_in[6];
    const float* gamma2 = (const float*)d_in[7];
    const float* beta2  = (const float*)d_in[8];
    float* out = (float*)d_out;

    char* ws = (char*)d_ws;
    u16*   featT = (u16*)(ws + 0);           //  4,194,304
    int*   idxp  = (int*)(ws + 4194304);     //  1,048,576
    u16*   gxyz  = (u16*)(ws + 5242880);     //  2,097,152
    u16*   Wp1   = (u16*)(ws + 7340032);     //    147,456
    u16*   Wp2   = (u16*)(ws + 7487488);     //    131,072
    float* ab1   = (float*)(ws + 7618560);   //      2,048
    float* ab2   = (float*)(ws + 7620608);   //      2,048
    float* cntx  = (float*)(ws + 7622656);   //    131,072  (8192 rows x 4 f32)
    float* Sacc  = (float*)(ws + 7753728);   //      1,024
    float* Qacc  = (float*)(ws + 7754752);   //      1,024
    float* Xacc  = (float*)(ws + 7755776);   //      1,024
    float* xst4  = (float*)(ws + 7756800);   //      1,024  (4 x 9 used)
    float* psum  = (float*)(ws + 7757824);   //  4,194,304
    float* psq   = (float*)(ws + 11952128);  //  4,194,304
    float* ymax  = (float*)(ws + 16146432);  //  8,388,608
    float* ymin  = (float*)(ws + 24535040);  //  8,388,608
    const size_t NEED = 32923648ull;

    // stage-2 reduction scratch (borrowed dead regions):
    //  - stats1 reduce (fallback) runs before pass 2 writes ymin -> borrow ymin
    //  - stats2 reduce runs after gxyz last use -> borrow gxyz
    float* r1s = (float*)(ws + 24535040);
    float* r1q = r1s + 16384;
    float* r2s = (float*)(ws + 5242880);
    float* r2q = r2s + 16384;

    prep_k<<<256, 256, 0, stream>>>(W1, W2, Wp1, Wp2);
    query_k<<<2048, 256, 0, stream>>>(xyz, rot, idxp);
    featT_k<<<dim3(64, 8, 4), 256, 0, stream>>>(feat, featT);
    gxyz_k<<<1024, 256, 0, stream>>>(xyz, rot, idxp, gxyz);

    if (ws_size >= NEED) {
        // stats1 via Gram decomposition over the 8192 unique gathered rows (no y1 materialization)
        zero_k<<<3, 256, 0, stream>>>(Sacc, 768);
        count2_k<<<4, 256, 0, stream>>>(idxp, gxyz, cntx, xst4);
        zgemm_k<<<NROW / 64, 256, 0, stream>>>(featT, Wp1, cntx, Sacc, Qacc, Xacc);
        ab1_k<<<1, 256, 0, stream>>>(Sacc, Qacc, Xacc, xst4, Wp1, gamma1, beta1, ab1);
        // single fused pass: GEMM1 -> norm1 (per-wave slices) -> GEMM2 -> stats2 + max/min
        full_k<<<NBLK, 256, 0, stream>>>(featT, gxyz, idxp, Wp1, Wp2, ab1, psum, psq, ymax, ymin);
        reduce1_k<<<64, 256, 0, stream>>>(psum, psq, r2s, r2q);
        reduce2_k<<<1, 256, 0, stream>>>(r2s, r2q, gamma2, beta2, ab2);
    } else {
        // fallback: recompute GEMM1 in pass 2 (round-2 proven path)
        fused_k<0><<<NBLK, 256, 0, stream>>>(featT, gxyz, idxp, Wp1, Wp2, ab1, psum, psq, ymax, ymin);
        reduce1_k<<<64, 256, 0, stream>>>(psum, psq, r1s, r1q);
        reduce2_k<<<1, 256, 0, stream>>>(r1s, r1q, gamma1, beta1, ab1);
        fused_k<1><<<NBLK, 256, 0, stream>>>(featT, gxyz, idxp, Wp1, Wp2, ab1, psum, psq, ymax, ymin);
        reduce1_k<<<64, 256, 0, stream>>>(psum, psq, r2s, r2q);
        reduce2_k<<<1, 256, 0, stream>>>(r2s, r2q, gamma2, beta2, ab2);
    }
    final_k<<<dim3(64, 8, 4), 256, 0, stream>>>(ymax, ymin, ab2, out);
}

// Round 5
// 283.385 us; speedup vs baseline: 3.1007x; 3.1007x over previous
//
#include <hip/hip_runtime.h>

typedef unsigned short u16;
typedef unsigned int u32;
typedef __attribute__((ext_vector_type(8))) short bf16x8;
typedef __attribute__((ext_vector_type(4))) float f32x4;

#define NPTS 2048
#define CFEAT 256
#define NS 32
#define MTOT 262144           // 4*2048*32
#define NBLK 4096             // MTOT/64 m-tiles
#define NROW 8192             // unique gathered rows = 4*2048
#define INV_N (1.0f/262144.0f)

__device__ __forceinline__ float bf2f(u16 u) {
    union { u32 i; float f; } v; v.i = ((u32)u) << 16; return v.f;
}
__device__ __forceinline__ u16 f2bf(float f) {
    union { float f; u32 i; } v; v.f = f;
    u32 i = v.i;
    return (u16)((i + 0x7fffu + ((i >> 16) & 1u)) >> 16);
}

// async global->LDS, 16B per lane. LDS dest = wave-uniform base + lane*16; global src per-lane.
__device__ __forceinline__ void gload16(const void* g, void* l) {
    __builtin_amdgcn_global_load_lds((const __attribute__((address_space(1))) void*)g,
                                     (__attribute__((address_space(3))) void*)l, 16, 0, 0);
}

// ---------------- prep: pack W1 -> [feat(256) | xyz(3) | 0(29)] (K=288), W2 (K=256), bf16 ----------------
__global__ __launch_bounds__(256) void prep_k(const float* __restrict__ W1, const float* __restrict__ W2,
                                              u16* __restrict__ Wp1, u16* __restrict__ Wp2) {
    int o = blockIdx.x, t = threadIdx.x;
    Wp1[o * 288 + t] = f2bf(W1[o * 259 + 3 + t]);
    if (t < 32) Wp1[o * 288 + 256 + t] = (t < 3) ? f2bf(W1[o * 259 + t]) : (u16)0;
    Wp2[o * 256 + t] = f2bf(W2[o * 256 + t]);
}

// ---------------- cylinder query: wave per point, ballot compaction ----------------
__global__ __launch_bounds__(256) void query_k(const float* __restrict__ xyz, const float* __restrict__ rot,
                                               int* __restrict__ idx) {
    int pid = blockIdx.x * 4 + (threadIdx.x >> 6);
    int lane = threadIdx.x & 63;
    int b = pid >> 11, p = pid & 2047;
    const float* xb = xyz + (size_t)b * NPTS * 3;
    float px = xb[p * 3 + 0], py = xb[p * 3 + 1], pz = xb[p * 3 + 2];
    const float* rp = rot + (size_t)pid * 9;
    float r00 = rp[0], r01 = rp[1], r02 = rp[2];
    float r10 = rp[3], r11 = rp[4], r12 = rp[5];
    float r20 = rp[6], r21 = rp[7], r22 = rp[8];
    int cnt = 0, first = 0;
    for (int n0 = 0; n0 < NPTS && cnt < NS; n0 += 64) {
        int n = n0 + lane;
        float dx = __fsub_rn(xb[n * 3 + 0], px);
        float dy = __fsub_rn(xb[n * 3 + 1], py);
        float dz = __fsub_rn(xb[n * 3 + 2], pz);
        float a0 = __fadd_rn(__fadd_rn(__fmul_rn(r00, dx), __fmul_rn(r01, dy)), __fmul_rn(r02, dz));
        float a1 = __fadd_rn(__fadd_rn(__fmul_rn(r10, dx), __fmul_rn(r11, dy)), __fmul_rn(r12, dz));
        float a2 = __fadd_rn(__fadd_rn(__fmul_rn(r20, dx), __fmul_rn(r21, dy)), __fmul_rn(r22, dz));
        float t2 = __fadd_rn(__fmul_rn(a1, a1), __fmul_rn(a2, a2));
        bool valid = (t2 < 0.0025f) && (a0 > -0.02f) && (a0 < 0.04f);
        unsigned long long bal = __ballot(valid);
        if (cnt == 0 && bal) first = n0 + __builtin_ctzll(bal);
        int rank = __builtin_popcountll(bal & ((1ull << lane) - 1ull));
        int slot = cnt + rank;
        if (valid && slot < NS) idx[(size_t)pid * NS + slot] = n;
        cnt += __builtin_popcountll(bal);
    }
    int filled = cnt < NS ? cnt : NS;
    if (lane >= filled && lane < NS) idx[(size_t)pid * NS + lane] = (cnt > 0) ? first : 0;
}

// ---------------- features (B,C,N) fp32 -> featT (B,N,C) bf16 ----------------
__global__ __launch_bounds__(256) void featT_k(const float* __restrict__ feat, u16* __restrict__ featT) {
    __shared__ float sm[32 * 33];
    int b = blockIdx.z;
    int n0 = blockIdx.x * 32, c0 = blockIdx.y * 32;
    int t = threadIdx.x, x = t & 31, y = t >> 5;
    #pragma unroll
    for (int rr = 0; rr < 4; rr++) {
        int c = c0 + y + rr * 8;
        sm[(y + rr * 8) * 33 + x] = feat[((size_t)(b * CFEAT + c)) * NPTS + n0 + x];
    }
    __syncthreads();
    #pragma unroll
    for (int rr = 0; rr < 4; rr++) {
        int n = n0 + y + rr * 8;
        featT[((size_t)(b * NPTS + n)) * CFEAT + c0 + x] = f2bf(sm[x * 33 + (y + rr * 8)]);
    }
}

// ---------------- gxyz: rotated, scaled neighbor offsets, (MTOT,4) bf16 ----------------
__global__ __launch_bounds__(256) void gxyz_k(const float* __restrict__ xyz, const float* __restrict__ rot,
                                              const int* __restrict__ idx, u16* __restrict__ gxyz) {
    int m = blockIdx.x * 256 + threadIdx.x;
    int pid = m >> 5;
    int b = pid >> 11, p = pid & 2047;
    int i = idx[m];
    const float* xb = xyz + (size_t)b * NPTS * 3;
    float dx = (xb[i * 3 + 0] - xb[p * 3 + 0]) * 20.0f;
    float dy = (xb[i * 3 + 1] - xb[p * 3 + 1]) * 20.0f;
    float dz = (xb[i * 3 + 2] - xb[p * 3 + 2]) * 20.0f;
    const float* rp = rot + (size_t)pid * 9;
    float g0 = dx * rp[0] + dy * rp[3] + dz * rp[6];
    float g1 = dx * rp[1] + dy * rp[4] + dz * rp[7];
    float g2 = dx * rp[2] + dy * rp[5] + dz * rp[8];
    uint2 v;
    v.x = (u32)f2bf(g0) | ((u32)f2bf(g1) << 16);
    v.y = (u32)f2bf(g2);
    *(uint2*)(gxyz + (size_t)m * 4) = v;
}

// ---------------- zero scratch ----------------
__global__ __launch_bounds__(256) void zero_k(float* __restrict__ p, int n) {
    int i = blockIdx.x * 256 + threadIdx.x;
    if (i < n) p[i] = 0.f;
}

// ---------------- histogram partials: 64 blocks (16/batch), private LDS hist, NO global atomics --------
// block g covers m in [g*4096,(g+1)*4096) (stays inside batch g>>4). Writes hpart[g][8192] and
// per-block xyz-moment partials xst64[g][9].
__global__ __launch_bounds__(256) void hist_k(const int* __restrict__ idx, const u16* __restrict__ gxyz,
                                              float* __restrict__ hpart, float* __restrict__ xst64) {
    __shared__ float hist[8192];       // 2048 rows x 4 (cnt,x0,x1,x2) = 32 KB
    __shared__ float red[9 * 4];
    const int t = threadIdx.x, lane = t & 63, wave = t >> 6;
    const int g = blockIdx.x;
    const int base = g * 4096;
    for (int i = t; i < 8192; i += 256) hist[i] = 0.f;
    __syncthreads();
    float p[9] = {0.f,0.f,0.f,0.f,0.f,0.f,0.f,0.f,0.f};
    for (int u = 0; u < 16; u++) {
        int m = base + u * 256 + t;
        int r = idx[m];                // local row 0..2047
        uint2 v = *(const uint2*)(gxyz + (size_t)m * 4);
        float x0 = bf2f((u16)(v.x & 0xffff));
        float x1 = bf2f((u16)(v.x >> 16));
        float x2 = bf2f((u16)(v.y & 0xffff));
        atomicAdd(hist + r * 4 + 0, 1.f);   // LDS atomics, ~4K spread over 2048*4 addrs
        atomicAdd(hist + r * 4 + 1, x0);
        atomicAdd(hist + r * 4 + 2, x1);
        atomicAdd(hist + r * 4 + 3, x2);
        p[0] += x0; p[1] += x1; p[2] += x2;
        p[3] += x0 * x0; p[4] += x0 * x1; p[5] += x0 * x2;
        p[6] += x1 * x1; p[7] += x1 * x2; p[8] += x2 * x2;
    }
    __syncthreads();
    for (int i = t; i < 8192; i += 256) hpart[(size_t)g * 8192 + i] = hist[i];
    #pragma unroll
    for (int k = 0; k < 9; k++) {
        float s = p[k];
        #pragma unroll
        for (int o = 1; o < 64; o <<= 1) s += __shfl_xor(s, o);
        if (lane == 0) red[k * 4 + wave] = s;
    }
    __syncthreads();
    if (t < 9) xst64[g * 9 + t] = red[t * 4 + 0] + red[t * 4 + 1] + red[t * 4 + 2] + red[t * 4 + 3];
}

// ---------------- merge 16 partials per batch -> cntx (coalesced) ----------------
__global__ __launch_bounds__(256) void merge_k(const float* __restrict__ hpart, float* __restrict__ cntx) {
    int i = blockIdx.x * 256 + threadIdx.x;     // 0..32767
    int b = i >> 13;                            // batch
    int off = i & 8191;
    float s = 0.f;
    #pragma unroll
    for (int sg = 0; sg < 16; sg++) s += hpart[(size_t)(b * 16 + sg) * 8192 + off];
    cntx[i] = s;
}

// ---------------- z-GEMM over the 8192 unique rows + fused weighted stats1 reduction ----------------
__global__ __launch_bounds__(256) void zgemm_k(const u16* __restrict__ featT, const u16* __restrict__ Wp1,
                                               const float* __restrict__ cntx,
                                               float* __restrict__ Sacc, float* __restrict__ Qacc,
                                               float* __restrict__ Xacc) {
    __shared__ __attribute__((aligned(16))) u16 As[64 * 32];
    __shared__ __attribute__((aligned(16))) u16 Bs[256 * 32];
    const int tid = threadIdx.x;
    const int lane = tid & 63, wave = tid >> 6;
    const int quad = lane >> 4, tl = lane & 15;
    const int m0 = blockIdx.x * 64;
    const int srow = tid >> 2, sc16 = tid & 3;
    const int abase = (m0 + srow) * CFEAT + sc16 * 8;

    f32x4 acc[4][4];
    #pragma unroll
    for (int i = 0; i < 4; i++)
        #pragma unroll
        for (int j = 0; j < 4; j++) acc[i][j] = (f32x4){0.f, 0.f, 0.f, 0.f};

    for (int ks = 0; ks < 8; ks++) {
        const int k0 = ks * 32;
        __syncthreads();
        gload16(featT + abase + k0, As + tid * 8);
        #pragma unroll
        for (int q = 0; q < 4; q++)
            gload16(Wp1 + (srow + q * 64) * 288 + k0 + sc16 * 8, Bs + q * 2048 + tid * 8);
        __syncthreads();
        bf16x8 af[4], bv[4];
        #pragma unroll
        for (int i = 0; i < 4; i++) af[i] = *(const bf16x8*)(As + (i * 16 + tl) * 32 + quad * 8);
        #pragma unroll
        for (int j = 0; j < 4; j++) bv[j] = *(const bf16x8*)(Bs + (wave * 64 + j * 16 + tl) * 32 + quad * 8);
        #pragma unroll
        for (int i = 0; i < 4; i++)
            #pragma unroll
            for (int j = 0; j < 4; j++)
                acc[i][j] = __builtin_amdgcn_mfma_f32_16x16x32_bf16(af[i], bv[j], acc[i][j], 0, 0, 0);
    }

    #pragma unroll
    for (int j = 0; j < 4; j++) {
        int col = wave * 64 + j * 16 + tl;
        float wx0 = bf2f(Wp1[col * 288 + 256]);
        float wx1 = bf2f(Wp1[col * 288 + 257]);
        float wx2 = bf2f(Wp1[col * 288 + 258]);
        float S = 0.f, Q = 0.f, X = 0.f;
        #pragma unroll
        for (int i = 0; i < 4; i++)
            #pragma unroll
            for (int rr = 0; rr < 4; rr++) {
                int row = i * 16 + quad * 4 + rr;
                float4 cx = *(const float4*)(cntx + (size_t)(m0 + row) * 4);
                float z = acc[i][j][rr];
                S += cx.x * z;
                Q += cx.x * z * z;
                X += z * (wx0 * cx.y + wx1 * cx.z + wx2 * cx.w);
            }
        S += __shfl_xor(S, 16); S += __shfl_xor(S, 32);
        Q += __shfl_xor(Q, 16); Q += __shfl_xor(Q, 32);
        X += __shfl_xor(X, 16); X += __shfl_xor(X, 32);
        if (quad == 0) {
            atomicAdd(Sacc + col, S);
            atomicAdd(Qacc + col, Q);
            atomicAdd(Xacc + col, X);
        }
    }
}

// ---------------- assemble stats1 -> (a,b) affine ----------------
__global__ __launch_bounds__(256) void ab1_k(const float* __restrict__ Sacc, const float* __restrict__ Qacc,
                                             const float* __restrict__ Xacc, const float* __restrict__ xst64,
                                             const u16* __restrict__ Wp1,
                                             const float* __restrict__ gamma, const float* __restrict__ beta,
                                             float* __restrict__ ab) {
    int c = threadIdx.x;
    float xs[9] = {0.f,0.f,0.f,0.f,0.f,0.f,0.f,0.f,0.f};
    for (int g = 0; g < 64; g++)
        #pragma unroll
        for (int k = 0; k < 9; k++) xs[k] += xst64[g * 9 + k];
    float wx0 = bf2f(Wp1[c * 288 + 256]);
    float wx1 = bf2f(Wp1[c * 288 + 257]);
    float wx2 = bf2f(Wp1[c * 288 + 258]);
    float S = Sacc[c] + wx0 * xs[0] + wx1 * xs[1] + wx2 * xs[2];
    float qxx = wx0 * wx0 * xs[3] + wx1 * wx1 * xs[6] + wx2 * wx2 * xs[8]
              + 2.f * (wx0 * wx1 * xs[4] + wx0 * wx2 * xs[5] + wx1 * wx2 * xs[7]);
    float Q = Qacc[c] + 2.f * Xacc[c] + qxx;
    float mu = S * INV_N;
    float var = Q * INV_N - mu * mu;
    float a = gamma[c] * rsqrtf(var + 1e-5f);
    ab[c] = a;
    ab[256 + c] = beta[c] - mu * a;
}

// ---------------- fused m-tile kernel (round-0/1 proven structure, two barriers per K-step) ----------
// FULL=0: GEMM1 + stats1 partials. FULL=1: GEMM1 -> norm1+relu -> y1s -> GEMM2 -> stats2 + max/min.
template <int FULL>
__global__ __launch_bounds__(256) void fused_k(
    const u16* __restrict__ featT, const u16* __restrict__ gxyz, const int* __restrict__ idx,
    const u16* __restrict__ Wp1, const u16* __restrict__ Wp2, const float* __restrict__ ab1,
    float* __restrict__ psum, float* __restrict__ psq,
    float* __restrict__ ymax, float* __restrict__ ymin)
{
    __shared__ __attribute__((aligned(16))) u16 As[64 * 32];
    __shared__ __attribute__((aligned(16))) u16 Bs[256 * 32];
    __shared__ __attribute__((aligned(16))) u16 y1s[FULL ? 64 * 264 : 16];
    __shared__ int rowbase_s[64];

    const int tid = threadIdx.x;
    const int lane = tid & 63, wave = tid >> 6;
    const int quad = lane >> 4, tl = lane & 15;
    const int bx = blockIdx.x;
    const int m0 = bx * 64;

    if (tid < 64) {
        int m = m0 + tid;
        int gi = idx[m];
        int b = m >> 16;
        rowbase_s[tid] = (b * NPTS + gi) * CFEAT;
    }
    __syncthreads();
    const int srow = tid >> 2, sc16 = tid & 3;
    const int abase = rowbase_s[srow] + sc16 * 8;

    f32x4 acc[4][4];
    #pragma unroll
    for (int i = 0; i < 4; i++)
        #pragma unroll
        for (int j = 0; j < 4; j++) acc[i][j] = (f32x4){0.f, 0.f, 0.f, 0.f};

    auto mfma_tile = [&](f32x4 (&ac)[4][4], const u16* a_lds, int a_stride) {
        bf16x8 af[4], bv[4];
        #pragma unroll
        for (int i = 0; i < 4; i++) af[i] = *(const bf16x8*)(a_lds + (i * 16 + tl) * a_stride + quad * 8);
        #pragma unroll
        for (int j = 0; j < 4; j++) bv[j] = *(const bf16x8*)(Bs + (wave * 64 + j * 16 + tl) * 32 + quad * 8);
        #pragma unroll
        for (int i = 0; i < 4; i++)
            #pragma unroll
            for (int j = 0; j < 4; j++)
                ac[i][j] = __builtin_amdgcn_mfma_f32_16x16x32_bf16(af[i], bv[j], ac[i][j], 0, 0, 0);
    };

    for (int ks = 0; ks < 8; ks++) {
        const int k0 = ks * 32;
        __syncthreads();
        gload16(featT + abase + k0, As + tid * 8);
        #pragma unroll
        for (int q = 0; q < 4; q++)
            gload16(Wp1 + (srow + q * 64) * 288 + k0 + sc16 * 8, Bs + q * 2048 + tid * 8);
        __syncthreads();
        mfma_tile(acc, As, 32);
    }
    {
        __syncthreads();
        uint4 va = make_uint4(0, 0, 0, 0);
        if (sc16 == 0) {
            uint2 g2 = *(const uint2*)(gxyz + (size_t)(m0 + srow) * 4);
            va.x = g2.x; va.y = g2.y;
        }
        *(uint4*)(As + srow * 32 + sc16 * 8) = va;
        #pragma unroll
        for (int q = 0; q < 4; q++)
            gload16(Wp1 + (srow + q * 64) * 288 + 256 + sc16 * 8, Bs + q * 2048 + tid * 8);
        __syncthreads();
        mfma_tile(acc, As, 32);
    }

    if (!FULL) {
        #pragma unroll
        for (int j = 0; j < 4; j++) {
            float s = 0.f, q2 = 0.f;
            #pragma unroll
            for (int i = 0; i < 4; i++) {
                s += acc[i][j][0] + acc[i][j][1] + acc[i][j][2] + acc[i][j][3];
                q2 += acc[i][j][0]*acc[i][j][0] + acc[i][j][1]*acc[i][j][1]
                    + acc[i][j][2]*acc[i][j][2] + acc[i][j][3]*acc[i][j][3];
            }
            s += __shfl_xor(s, 16); s += __shfl_xor(s, 32);
            q2 += __shfl_xor(q2, 16); q2 += __shfl_xor(q2, 32);
            if (quad == 0) {
                int col = wave * 64 + j * 16 + tl;
                psum[(size_t)bx * 256 + col] = s;
                psq[(size_t)bx * 256 + col] = q2;
            }
        }
        return;
    }

    #pragma unroll
    for (int j = 0; j < 4; j++) {
        int col = wave * 64 + j * 16 + tl;
        float a = ab1[col], bb = ab1[256 + col];
        #pragma unroll
        for (int i = 0; i < 4; i++)
            #pragma unroll
            for (int r = 0; r < 4; r++) {
                float v = fmaxf(fmaf(acc[i][j][r], a, bb), 0.f);
                y1s[(i * 16 + quad * 4 + r) * 264 + col] = f2bf(v);
            }
    }

    f32x4 acc2[4][4];
    #pragma unroll
    for (int i = 0; i < 4; i++)
        #pragma unroll
        for (int j = 0; j < 4; j++) acc2[i][j] = (f32x4){0.f, 0.f, 0.f, 0.f};
    for (int ks = 0; ks < 8; ks++) {
        const int k0 = ks * 32;
        __syncthreads();
        #pragma unroll
        for (int q = 0; q < 4; q++)
            gload16(Wp2 + (srow + q * 64) * 256 + k0 + sc16 * 8, Bs + q * 2048 + tid * 8);
        __syncthreads();
        mfma_tile(acc2, y1s + k0, 264);
    }

    #pragma unroll
    for (int j = 0; j < 4; j++) {
        int col = wave * 64 + j * 16 + tl;
        float s = 0.f, q2 = 0.f;
        float mx0 = -3.0e38f, mn0 = 3.0e38f, mx1 = -3.0e38f, mn1 = 3.0e38f;
        #pragma unroll
        for (int i = 0; i < 4; i++)
            #pragma unroll
            for (int r = 0; r < 4; r++) {
                float v = acc2[i][j][r];
                s += v; q2 += v * v;
                if (i < 2) { mx0 = fmaxf(mx0, v); mn0 = fminf(mn0, v); }
                else       { mx1 = fmaxf(mx1, v); mn1 = fminf(mn1, v); }
            }
        s += __shfl_xor(s, 16); s += __shfl_xor(s, 32);
        q2 += __shfl_xor(q2, 16); q2 += __shfl_xor(q2, 32);
        mx0 = fmaxf(mx0, __shfl_xor(mx0, 16)); mx0 = fmaxf(mx0, __shfl_xor(mx0, 32));
        mn0 = fminf(mn0, __shfl_xor(mn0, 16)); mn0 = fminf(mn0, __shfl_xor(mn0, 32));
        mx1 = fmaxf(mx1, __shfl_xor(mx1, 16)); mx1 = fmaxf(mx1, __shfl_xor(mx1, 32));
        mn1 = fminf(mn1, __shfl_xor(mn1, 16)); mn1 = fminf(mn1, __shfl_xor(mn1, 32));
        if (quad == 0) {
            psum[(size_t)bx * 256 + col] = s;
            psq[(size_t)bx * 256 + col] = q2;
            size_t p0 = (size_t)(bx * 2) * 256 + col;
            size_t p1 = (size_t)(bx * 2 + 1) * 256 + col;
            ymax[p0] = mx0; ymin[p0] = mn0;
            ymax[p1] = mx1; ymin[p1] = mn1;
        }
    }
}

// ---------------- stats reduction: 64 blocks x 64 rows (coalesced), then 1-block finish ----------------
__global__ __launch_bounds__(256) void reduce1_k(const float* __restrict__ psum, const float* __restrict__ psq,
                                                 float* __restrict__ ps2, float* __restrict__ pq2) {
    int j = blockIdx.x, t = threadIdx.x;
    float s = 0.f, q = 0.f;
    #pragma unroll 4
    for (int kk = 0; kk < 64; kk++) {
        size_t r = (size_t)(j * 64 + kk) * 256 + t;
        s += psum[r]; q += psq[r];
    }
    ps2[j * 256 + t] = s;
    pq2[j * 256 + t] = q;
}

__global__ __launch_bounds__(256) void reduce2_k(const float* __restrict__ ps2, const float* __restrict__ pq2,
                                                 const float* __restrict__ gamma, const float* __restrict__ beta,
                                                 float* __restrict__ ab) {
    int c = threadIdx.x;
    float S = 0.f, Q = 0.f;
    for (int j = 0; j < 64; j++) {
        S += ps2[j * 256 + c];
        Q += pq2[j * 256 + c];
    }
    float mu = S * INV_N;
    float var = Q * INV_N - mu * mu;
    float a = gamma[c] * rsqrtf(var + 1e-5f);
    ab[c] = a;
    ab[256 + c] = beta[c] - mu * a;
}

// ---------------- final: relu(a*(a>=0?max:min)+b), transpose -> (B,O,N) ----------------
__global__ __launch_bounds__(256) void final_k(const float* __restrict__ ymax, const float* __restrict__ ymin,
                                               const float* __restrict__ ab, float* __restrict__ out) {
    __shared__ float sm[32 * 33];
    int b = blockIdx.z;
    int n0 = blockIdx.x * 32, o0 = blockIdx.y * 32;
    int t = threadIdx.x, x = t & 31, y = t >> 5;
    #pragma unroll
    for (int rr = 0; rr < 4; rr++) {
        int n = n0 + y + rr * 8;
        int o = o0 + x;
        float a = ab[o], bb = ab[256 + o];
        size_t p = (size_t)(b * NPTS + n) * 256 + o;
        float v = (a >= 0.f) ? ymax[p] : ymin[p];
        sm[(y + rr * 8) * 33 + x] = fmaxf(fmaf(v, a, bb), 0.f);
    }
    __syncthreads();
    #pragma unroll
    for (int rr = 0; rr < 4; rr++)
        out[((size_t)(b * 256 + o0 + y + rr * 8)) * NPTS + n0 + x] = sm[x * 33 + (y + rr * 8)];
}

extern "C" void kernel_launch(void* const* d_in, const int* in_sizes, int n_in,
                              void* d_out, int out_size, void* d_ws, size_t ws_size,
                              hipStream_t stream) {
    const float* xyz    = (const float*)d_in[0];
    const float* feat   = (const float*)d_in[1];
    const float* rot    = (const float*)d_in[2];
    const float* W1     = (const float*)d_in[3];
    const float* gamma1 = (const float*)d_in[4];
    const float* beta1  = (const float*)d_in[5];
    const float* W2     = (const float*)d_in[6];
    const float* gamma2 = (const float*)d_in[7];
    const float* beta2  = (const float*)d_in[8];
    float* out = (float*)d_out;

    char* ws = (char*)d_ws;
    u16*   featT = (u16*)(ws + 0);           //  4,194,304
    int*   idxp  = (int*)(ws + 4194304);     //  1,048,576
    u16*   gxyz  = (u16*)(ws + 5242880);     //  2,097,152
    u16*   Wp1   = (u16*)(ws + 7340032);     //    147,456
    u16*   Wp2   = (u16*)(ws + 7487488);     //    131,072
    float* ab1   = (float*)(ws + 7618560);   //      2,048
    float* ab2   = (float*)(ws + 7620608);   //      2,048
    float* cntx  = (float*)(ws + 7622656);   //    131,072  (8192 rows x 4 f32)
    float* Sacc  = (float*)(ws + 7753728);   //      1,024
    float* Qacc  = (float*)(ws + 7754752);   //      1,024
    float* Xacc  = (float*)(ws + 7755776);   //      1,024
    float* xst64 = (float*)(ws + 7756800);   //      4,096  (64 x 9 used)
    float* hpart = (float*)(ws + 7760896);   //  2,097,152  (64 x 8192 f32)
    float* psum  = (float*)(ws + 9858048);   //  4,194,304
    float* psq   = (float*)(ws + 14052352);  //  4,194,304
    float* ymax  = (float*)(ws + 18246656);  //  8,388,608
    float* ymin  = (float*)(ws + 26635264);  //  8,388,608
    const size_t NEED = 35023872ull;

    // stage-2 reduction scratch (borrowed dead regions):
    //  - stats1 reduce (fallback) runs before pass 2 writes ymin -> borrow ymin
    //  - stats2 reduce runs after gxyz last use -> borrow gxyz
    float* r1s = (float*)(ws + 26635264);
    float* r1q = r1s + 16384;
    float* r2s = (float*)(ws + 5242880);
    float* r2q = r2s + 16384;

    prep_k<<<256, 256, 0, stream>>>(W1, W2, Wp1, Wp2);
    query_k<<<2048, 256, 0, stream>>>(xyz, rot, idxp);
    featT_k<<<dim3(64, 8, 4), 256, 0, stream>>>(feat, featT);
    gxyz_k<<<1024, 256, 0, stream>>>(xyz, rot, idxp, gxyz);

    if (ws_size >= NEED) {
        // stats1 via Gram decomposition over the 8192 unique gathered rows (no y1 materialization)
        zero_k<<<3, 256, 0, stream>>>(Sacc, 768);
        hist_k<<<64, 256, 0, stream>>>(idxp, gxyz, hpart, xst64);
        merge_k<<<128, 256, 0, stream>>>(hpart, cntx);
        zgemm_k<<<NROW / 64, 256, 0, stream>>>(featT, Wp1, cntx, Sacc, Qacc, Xacc);
        ab1_k<<<1, 256, 0, stream>>>(Sacc, Qacc, Xacc, xst64, Wp1, gamma1, beta1, ab1);
        // single heavy pass (proven structure): GEMM1 -> norm1 -> GEMM2 -> stats2 + max/min
        fused_k<1><<<NBLK, 256, 0, stream>>>(featT, gxyz, idxp, Wp1, Wp2, ab1, psum, psq, ymax, ymin);
        reduce1_k<<<64, 256, 0, stream>>>(psum, psq, r2s, r2q);
        reduce2_k<<<1, 256, 0, stream>>>(r2s, r2q, gamma2, beta2, ab2);
    } else {
        // fallback: recompute GEMM1 in pass 2 (round-2 proven path)
        fused_k<0><<<NBLK, 256, 0, stream>>>(featT, gxyz, idxp, Wp1, Wp2, ab1, psum, psq, ymax, ymin);
        reduce1_k<<<64, 256, 0, stream>>>(psum, psq, r1s, r1q);
        reduce2_k<<<1, 256, 0, stream>>>(r1s, r1q, gamma1, beta1, ab1);
        fused_k<1><<<NBLK, 256, 0, stream>>>(featT, gxyz, idxp, Wp1, Wp2, ab1, psum, psq, ymax, ymin);
        reduce1_k<<<64, 256, 0, stream>>>(psum, psq, r2s, r2q);
        reduce2_k<<<1, 256, 0, stream>>>(r2s, r2q, gamma2, beta2, ab2);
    }
    final_k<<<dim3(64, 8, 4), 256, 0, stream>>>(ymax, ymin, ab2, out);
}

// Round 6
// 267.387 us; speedup vs baseline: 3.2863x; 1.0598x over previous
//
#include <hip/hip_runtime.h>

typedef unsigned short u16;
typedef unsigned int u32;
typedef __attribute__((ext_vector_type(8))) short bf16x8;
typedef __attribute__((ext_vector_type(4))) float f32x4;

#define NPTS 2048
#define CFEAT 256
#define NS 32
#define MTOT 262144           // 4*2048*32
#define NBLK 4096             // MTOT/64 m-tiles
#define NROW 8192             // unique gathered rows = 4*2048
#define INV_N (1.0f/262144.0f)

__device__ __forceinline__ float bf2f(u16 u) {
    union { u32 i; float f; } v; v.i = ((u32)u) << 16; return v.f;
}
__device__ __forceinline__ u16 f2bf(float f) {
    union { float f; u32 i; } v; v.f = f;
    u32 i = v.i;
    return (u16)((i + 0x7fffu + ((i >> 16) & 1u)) >> 16);
}

// async global->LDS, 16B per lane. LDS dest = wave-uniform base + lane*16; global src per-lane.
__device__ __forceinline__ void gload16(const void* g, void* l) {
    __builtin_amdgcn_global_load_lds((const __attribute__((address_space(1))) void*)g,
                                     (__attribute__((address_space(3))) void*)l, 16, 0, 0);
}

// ---------------- prep: pack W1 -> [feat(256) | xyz(3) | 0(29)] (K=288), W2 (K=256), bf16 ----------------
__global__ __launch_bounds__(256) void prep_k(const float* __restrict__ W1, const float* __restrict__ W2,
                                              u16* __restrict__ Wp1, u16* __restrict__ Wp2) {
    int o = blockIdx.x, t = threadIdx.x;
    Wp1[o * 288 + t] = f2bf(W1[o * 259 + 3 + t]);
    if (t < 32) Wp1[o * 288 + 256 + t] = (t < 3) ? f2bf(W1[o * 259 + t]) : (u16)0;
    Wp2[o * 256 + t] = f2bf(W2[o * 256 + t]);
}

// ---------------- cylinder query: wave per point, ballot compaction ----------------
__global__ __launch_bounds__(256) void query_k(const float* __restrict__ xyz, const float* __restrict__ rot,
                                               int* __restrict__ idx) {
    int pid = blockIdx.x * 4 + (threadIdx.x >> 6);
    int lane = threadIdx.x & 63;
    int b = pid >> 11, p = pid & 2047;
    const float* xb = xyz + (size_t)b * NPTS * 3;
    float px = xb[p * 3 + 0], py = xb[p * 3 + 1], pz = xb[p * 3 + 2];
    const float* rp = rot + (size_t)pid * 9;
    float r00 = rp[0], r01 = rp[1], r02 = rp[2];
    float r10 = rp[3], r11 = rp[4], r12 = rp[5];
    float r20 = rp[6], r21 = rp[7], r22 = rp[8];
    int cnt = 0, first = 0;
    for (int n0 = 0; n0 < NPTS && cnt < NS; n0 += 64) {
        int n = n0 + lane;
        float dx = __fsub_rn(xb[n * 3 + 0], px);
        float dy = __fsub_rn(xb[n * 3 + 1], py);
        float dz = __fsub_rn(xb[n * 3 + 2], pz);
        float a0 = __fadd_rn(__fadd_rn(__fmul_rn(r00, dx), __fmul_rn(r01, dy)), __fmul_rn(r02, dz));
        float a1 = __fadd_rn(__fadd_rn(__fmul_rn(r10, dx), __fmul_rn(r11, dy)), __fmul_rn(r12, dz));
        float a2 = __fadd_rn(__fadd_rn(__fmul_rn(r20, dx), __fmul_rn(r21, dy)), __fmul_rn(r22, dz));
        float t2 = __fadd_rn(__fmul_rn(a1, a1), __fmul_rn(a2, a2));
        bool valid = (t2 < 0.0025f) && (a0 > -0.02f) && (a0 < 0.04f);
        unsigned long long bal = __ballot(valid);
        if (cnt == 0 && bal) first = n0 + __builtin_ctzll(bal);
        int rank = __builtin_popcountll(bal & ((1ull << lane) - 1ull));
        int slot = cnt + rank;
        if (valid && slot < NS) idx[(size_t)pid * NS + slot] = n;
        cnt += __builtin_popcountll(bal);
    }
    int filled = cnt < NS ? cnt : NS;
    if (lane >= filled && lane < NS) idx[(size_t)pid * NS + lane] = (cnt > 0) ? first : 0;
}

// ---------------- features (B,C,N) fp32 -> featT (B,N,C) bf16 ----------------
__global__ __launch_bounds__(256) void featT_k(const float* __restrict__ feat, u16* __restrict__ featT) {
    __shared__ float sm[32 * 33];
    int b = blockIdx.z;
    int n0 = blockIdx.x * 32, c0 = blockIdx.y * 32;
    int t = threadIdx.x, x = t & 31, y = t >> 5;
    #pragma unroll
    for (int rr = 0; rr < 4; rr++) {
        int c = c0 + y + rr * 8;
        sm[(y + rr * 8) * 33 + x] = feat[((size_t)(b * CFEAT + c)) * NPTS + n0 + x];
    }
    __syncthreads();
    #pragma unroll
    for (int rr = 0; rr < 4; rr++) {
        int n = n0 + y + rr * 8;
        featT[((size_t)(b * NPTS + n)) * CFEAT + c0 + x] = f2bf(sm[x * 33 + (y + rr * 8)]);
    }
}

// ---------------- gxyz: rotated, scaled neighbor offsets, (MTOT,4) bf16 ----------------
__global__ __launch_bounds__(256) void gxyz_k(const float* __restrict__ xyz, const float* __restrict__ rot,
                                              const int* __restrict__ idx, u16* __restrict__ gxyz) {
    int m = blockIdx.x * 256 + threadIdx.x;
    int pid = m >> 5;
    int b = pid >> 11, p = pid & 2047;
    int i = idx[m];
    const float* xb = xyz + (size_t)b * NPTS * 3;
    float dx = (xb[i * 3 + 0] - xb[p * 3 + 0]) * 20.0f;
    float dy = (xb[i * 3 + 1] - xb[p * 3 + 1]) * 20.0f;
    float dz = (xb[i * 3 + 2] - xb[p * 3 + 2]) * 20.0f;
    const float* rp = rot + (size_t)pid * 9;
    float g0 = dx * rp[0] + dy * rp[3] + dz * rp[6];
    float g1 = dx * rp[1] + dy * rp[4] + dz * rp[7];
    float g2 = dx * rp[2] + dy * rp[5] + dz * rp[8];
    uint2 v;
    v.x = (u32)f2bf(g0) | ((u32)f2bf(g1) << 16);
    v.y = (u32)f2bf(g2);
    *(uint2*)(gxyz + (size_t)m * 4) = v;
}

// ---------------- histogram partials: 64 blocks (16/batch), private LDS hist, NO global atomics --------
__global__ __launch_bounds__(256) void hist_k(const int* __restrict__ idx, const u16* __restrict__ gxyz,
                                              float* __restrict__ hpart, float* __restrict__ xst64) {
    __shared__ float hist[8192];       // 2048 rows x 4 (cnt,x0,x1,x2) = 32 KB
    __shared__ float red[9 * 4];
    const int t = threadIdx.x, lane = t & 63, wave = t >> 6;
    const int g = blockIdx.x;
    const int base = g * 4096;
    for (int i = t; i < 8192; i += 256) hist[i] = 0.f;
    __syncthreads();
    float p[9] = {0.f,0.f,0.f,0.f,0.f,0.f,0.f,0.f,0.f};
    for (int u = 0; u < 16; u++) {
        int m = base + u * 256 + t;
        int r = idx[m];                // local row 0..2047
        uint2 v = *(const uint2*)(gxyz + (size_t)m * 4);
        float x0 = bf2f((u16)(v.x & 0xffff));
        float x1 = bf2f((u16)(v.x >> 16));
        float x2 = bf2f((u16)(v.y & 0xffff));
        atomicAdd(hist + r * 4 + 0, 1.f);   // LDS atomics (ds_add_f32)
        atomicAdd(hist + r * 4 + 1, x0);
        atomicAdd(hist + r * 4 + 2, x1);
        atomicAdd(hist + r * 4 + 3, x2);
        p[0] += x0; p[1] += x1; p[2] += x2;
        p[3] += x0 * x0; p[4] += x0 * x1; p[5] += x0 * x2;
        p[6] += x1 * x1; p[7] += x1 * x2; p[8] += x2 * x2;
    }
    __syncthreads();
    for (int i = t; i < 8192; i += 256) hpart[(size_t)g * 8192 + i] = hist[i];
    #pragma unroll
    for (int k = 0; k < 9; k++) {
        float s = p[k];
        #pragma unroll
        for (int o = 1; o < 64; o <<= 1) s += __shfl_xor(s, o);
        if (lane == 0) red[k * 4 + wave] = s;
    }
    __syncthreads();
    if (t < 9) xst64[g * 9 + t] = red[t * 4 + 0] + red[t * 4 + 1] + red[t * 4 + 2] + red[t * 4 + 3];
}

// ---------------- z-GEMM over the 8192 unique rows + inline hpart merge + weighted stats1 ----------------
__global__ __launch_bounds__(256) void zgemm_k(const u16* __restrict__ featT, const u16* __restrict__ Wp1,
                                               const float* __restrict__ hpart,
                                               float* __restrict__ Sacc, float* __restrict__ Qacc,
                                               float* __restrict__ Xacc) {
    __shared__ __attribute__((aligned(16))) u16 As[64 * 32];
    __shared__ __attribute__((aligned(16))) u16 Bs[256 * 32];
    __shared__ float cxs[64 * 4];      // merged (cnt,x0,x1,x2) for this block's 64 rows
    const int tid = threadIdx.x;
    const int lane = tid & 63, wave = tid >> 6;
    const int quad = lane >> 4, tl = lane & 15;
    const int m0 = blockIdx.x * 64;
    const int srow = tid >> 2, sc16 = tid & 3;
    const int abase = (m0 + srow) * CFEAT + sc16 * 8;

    // inline merge of the 16 per-segment histogram partials for this block's rows (batch-local)
    {
        const int b = m0 >> 11;            // batch
        const int rl0 = m0 & 2047;         // local row base
        int row = tid >> 2, c = tid & 3;
        float s = 0.f;
        #pragma unroll
        for (int sg = 0; sg < 16; sg++)
            s += hpart[(size_t)(b * 16 + sg) * 8192 + (rl0 + row) * 4 + c];
        cxs[tid] = s;
    }

    f32x4 acc[4][4];
    #pragma unroll
    for (int i = 0; i < 4; i++)
        #pragma unroll
        for (int j = 0; j < 4; j++) acc[i][j] = (f32x4){0.f, 0.f, 0.f, 0.f};

    for (int ks = 0; ks < 8; ks++) {
        const int k0 = ks * 32;
        __syncthreads();
        gload16(featT + abase + k0, As + tid * 8);
        #pragma unroll
        for (int q = 0; q < 4; q++)
            gload16(Wp1 + (srow + q * 64) * 288 + k0 + sc16 * 8, Bs + q * 2048 + tid * 8);
        __syncthreads();
        bf16x8 af[4], bv[4];
        #pragma unroll
        for (int i = 0; i < 4; i++) af[i] = *(const bf16x8*)(As + (i * 16 + tl) * 32 + quad * 8);
        #pragma unroll
        for (int j = 0; j < 4; j++) bv[j] = *(const bf16x8*)(Bs + (wave * 64 + j * 16 + tl) * 32 + quad * 8);
        #pragma unroll
        for (int i = 0; i < 4; i++)
            #pragma unroll
            for (int j = 0; j < 4; j++)
                acc[i][j] = __builtin_amdgcn_mfma_f32_16x16x32_bf16(af[i], bv[j], acc[i][j], 0, 0, 0);
    }

    #pragma unroll
    for (int j = 0; j < 4; j++) {
        int col = wave * 64 + j * 16 + tl;
        float wx0 = bf2f(Wp1[col * 288 + 256]);
        float wx1 = bf2f(Wp1[col * 288 + 257]);
        float wx2 = bf2f(Wp1[col * 288 + 258]);
        float S = 0.f, Q = 0.f, X = 0.f;
        #pragma unroll
        for (int i = 0; i < 4; i++)
            #pragma unroll
            for (int rr = 0; rr < 4; rr++) {
                int row = i * 16 + quad * 4 + rr;
                float4 cx = *(const float4*)(cxs + row * 4);
                float z = acc[i][j][rr];
                S += cx.x * z;
                Q += cx.x * z * z;
                X += z * (wx0 * cx.y + wx1 * cx.z + wx2 * cx.w);
            }
        S += __shfl_xor(S, 16); S += __shfl_xor(S, 32);
        Q += __shfl_xor(Q, 16); Q += __shfl_xor(Q, 32);
        X += __shfl_xor(X, 16); X += __shfl_xor(X, 32);
        if (quad == 0) {
            atomicAdd(Sacc + col, S);
            atomicAdd(Qacc + col, Q);
            atomicAdd(Xacc + col, X);
        }
    }
}

// ---------------- assemble stats1 -> (a,b) affine ----------------
__global__ __launch_bounds__(256) void ab1_k(const float* __restrict__ Sacc, const float* __restrict__ Qacc,
                                             const float* __restrict__ Xacc, const float* __restrict__ xst64,
                                             const u16* __restrict__ Wp1,
                                             const float* __restrict__ gamma, const float* __restrict__ beta,
                                             float* __restrict__ ab) {
    int c = threadIdx.x;
    float xs[9] = {0.f,0.f,0.f,0.f,0.f,0.f,0.f,0.f,0.f};
    for (int g = 0; g < 64; g++)
        #pragma unroll
        for (int k = 0; k < 9; k++) xs[k] += xst64[g * 9 + k];
    float wx0 = bf2f(Wp1[c * 288 + 256]);
    float wx1 = bf2f(Wp1[c * 288 + 257]);
    float wx2 = bf2f(Wp1[c * 288 + 258]);
    float S = Sacc[c] + wx0 * xs[0] + wx1 * xs[1] + wx2 * xs[2];
    float qxx = wx0 * wx0 * xs[3] + wx1 * wx1 * xs[6] + wx2 * wx2 * xs[8]
              + 2.f * (wx0 * wx1 * xs[4] + wx0 * wx2 * xs[5] + wx1 * wx2 * xs[7]);
    float Q = Qacc[c] + 2.f * Xacc[c] + qxx;
    float mu = S * INV_N;
    float var = Q * INV_N - mu * mu;
    float a = gamma[c] * rsqrtf(var + 1e-5f);
    ab[c] = a;
    ab[256 + c] = beta[c] - mu * a;
}

// ---------------- fused m-tile kernel (two barriers per K-step, proven staging) --------------------
// col ownership remapped: col = j*64 + wave*16 + tl  (each wave owns 2 j-tiles per K-half of y1)
// FULL=0: GEMM1 + stats1 partials. FULL=1: GEMM1 -> norm1+relu (K-halved y1s) -> GEMM2 -> stats2+max/min.
// y1s half-buffer 64x136 (17 KB): channels 0..127 for GEMM2 ks=0..3, then overwritten with 128..255.
template <int FULL>
__global__ __launch_bounds__(256, 3) void fused_k(
    const u16* __restrict__ featT, const u16* __restrict__ gxyz, const int* __restrict__ idx,
    const u16* __restrict__ Wp1, const u16* __restrict__ Wp2, const float* __restrict__ ab1,
    float* __restrict__ psum, float* __restrict__ psq,
    float* __restrict__ ymax, float* __restrict__ ymin)
{
    __shared__ __attribute__((aligned(16))) u16 As[64 * 32];                 //  4 KB
    __shared__ __attribute__((aligned(16))) u16 Bs[256 * 32];                // 16 KB
    __shared__ __attribute__((aligned(16))) u16 y1s[FULL ? 64 * 136 : 16];   // 17 KB (half of y1)
    __shared__ int rowbase_s[64];

    const int tid = threadIdx.x;
    const int lane = tid & 63, wave = tid >> 6;
    const int quad = lane >> 4, tl = lane & 15;
    const int bx = blockIdx.x;
    const int m0 = bx * 64;

    if (tid < 64) {
        int m = m0 + tid;
        int gi = idx[m];
        int b = m >> 16;
        rowbase_s[tid] = (b * NPTS + gi) * CFEAT;
    }
    __syncthreads();
    const int srow = tid >> 2, sc16 = tid & 3;
    const int abase = rowbase_s[srow] + sc16 * 8;

    f32x4 acc[4][4];
    #pragma unroll
    for (int i = 0; i < 4; i++)
        #pragma unroll
        for (int j = 0; j < 4; j++) acc[i][j] = (f32x4){0.f, 0.f, 0.f, 0.f};

    auto mfma_tile = [&](f32x4 (&ac)[4][4], const u16* a_lds, int a_stride) {
        bf16x8 af[4], bv[4];
        #pragma unroll
        for (int i = 0; i < 4; i++) af[i] = *(const bf16x8*)(a_lds + (i * 16 + tl) * a_stride + quad * 8);
        #pragma unroll
        for (int j = 0; j < 4; j++) bv[j] = *(const bf16x8*)(Bs + (j * 64 + wave * 16 + tl) * 32 + quad * 8);
        #pragma unroll
        for (int i = 0; i < 4; i++)
            #pragma unroll
            for (int j = 0; j < 4; j++)
                ac[i][j] = __builtin_amdgcn_mfma_f32_16x16x32_bf16(af[i], bv[j], ac[i][j], 0, 0, 0);
    };

    // ---- GEMM1: 8 feat K-tiles + 1 xyz tile ----
    for (int ks = 0; ks < 8; ks++) {
        const int k0 = ks * 32;
        __syncthreads();
        gload16(featT + abase + k0, As + tid * 8);
        #pragma unroll
        for (int q = 0; q < 4; q++)
            gload16(Wp1 + (srow + q * 64) * 288 + k0 + sc16 * 8, Bs + q * 2048 + tid * 8);
        __syncthreads();
        mfma_tile(acc, As, 32);
    }
    {
        __syncthreads();
        uint4 va = make_uint4(0, 0, 0, 0);
        if (sc16 == 0) {
            uint2 g2 = *(const uint2*)(gxyz + (size_t)(m0 + srow) * 4);
            va.x = g2.x; va.y = g2.y;
        }
        *(uint4*)(As + srow * 32 + sc16 * 8) = va;
        #pragma unroll
        for (int q = 0; q < 4; q++)
            gload16(Wp1 + (srow + q * 64) * 288 + 256 + sc16 * 8, Bs + q * 2048 + tid * 8);
        __syncthreads();
        mfma_tile(acc, As, 32);
    }

    if (!FULL) {
        #pragma unroll
        for (int j = 0; j < 4; j++) {
            float s = 0.f, q2 = 0.f;
            #pragma unroll
            for (int i = 0; i < 4; i++) {
                s += acc[i][j][0] + acc[i][j][1] + acc[i][j][2] + acc[i][j][3];
                q2 += acc[i][j][0]*acc[i][j][0] + acc[i][j][1]*acc[i][j][1]
                    + acc[i][j][2]*acc[i][j][2] + acc[i][j][3]*acc[i][j][3];
            }
            s += __shfl_xor(s, 16); s += __shfl_xor(s, 32);
            q2 += __shfl_xor(q2, 16); q2 += __shfl_xor(q2, 32);
            if (quad == 0) {
                int col = j * 64 + wave * 16 + tl;
                psum[(size_t)bx * 256 + col] = s;
                psq[(size_t)bx * 256 + col] = q2;
            }
        }
        return;
    }

    // ---- norm1+relu, K-half 0 (channels 0..127 = j-tiles 0,1 of every wave) ----
    #pragma unroll
    for (int j = 0; j < 2; j++) {
        int col = j * 64 + wave * 16 + tl;          // < 128
        float a = ab1[col], bb = ab1[256 + col];
        #pragma unroll
        for (int i = 0; i < 4; i++)
            #pragma unroll
            for (int r = 0; r < 4; r++) {
                float v = fmaxf(fmaf(acc[i][j][r], a, bb), 0.f);
                y1s[(i * 16 + quad * 4 + r) * 136 + col] = f2bf(v);
            }
    }

    // ---- GEMM2: 8 K-steps; A = y1s half-buffer (swapped at ks==4), B = Wp2 tiles ----
    f32x4 acc2[4][4];
    #pragma unroll
    for (int i = 0; i < 4; i++)
        #pragma unroll
        for (int j = 0; j < 4; j++) acc2[i][j] = (f32x4){0.f, 0.f, 0.f, 0.f};
    for (int ks = 0; ks < 8; ks++) {
        if (ks == 4) {
            __syncthreads();                         // all ks=3 reads of y1s done
            #pragma unroll
            for (int j = 2; j < 4; j++) {            // channels 128..255
                int col = j * 64 + wave * 16 + tl;
                int lc = col - 128;
                float a = ab1[col], bb = ab1[256 + col];
                #pragma unroll
                for (int i = 0; i < 4; i++)
                    #pragma unroll
                    for (int r = 0; r < 4; r++) {
                        float v = fmaxf(fmaf(acc[i][j][r], a, bb), 0.f);
                        y1s[(i * 16 + quad * 4 + r) * 136 + lc] = f2bf(v);
                    }
            }
        }
        const int k0 = ks * 32;
        const int kl = k0 & 127;
        __syncthreads();
        #pragma unroll
        for (int q = 0; q < 4; q++)
            gload16(Wp2 + (srow + q * 64) * 256 + k0 + sc16 * 8, Bs + q * 2048 + tid * 8);
        __syncthreads();
        mfma_tile(acc2, y1s + kl, 136);
    }

    // ---- epilogue: stats2 + per-point max/min ----
    #pragma unroll
    for (int j = 0; j < 4; j++) {
        int col = j * 64 + wave * 16 + tl;
        float s = 0.f, q2 = 0.f;
        float mx0 = -3.0e38f, mn0 = 3.0e38f, mx1 = -3.0e38f, mn1 = 3.0e38f;
        #pragma unroll
        for (int i = 0; i < 4; i++)
            #pragma unroll
            for (int r = 0; r < 4; r++) {
                float v = acc2[i][j][r];
                s += v; q2 += v * v;
                if (i < 2) { mx0 = fmaxf(mx0, v); mn0 = fminf(mn0, v); }
                else       { mx1 = fmaxf(mx1, v); mn1 = fminf(mn1, v); }
            }
        s += __shfl_xor(s, 16); s += __shfl_xor(s, 32);
        q2 += __shfl_xor(q2, 16); q2 += __shfl_xor(q2, 32);
        mx0 = fmaxf(mx0, __shfl_xor(mx0, 16)); mx0 = fmaxf(mx0, __shfl_xor(mx0, 32));
        mn0 = fminf(mn0, __shfl_xor(mn0, 16)); mn0 = fminf(mn0, __shfl_xor(mn0, 32));
        mx1 = fmaxf(mx1, __shfl_xor(mx1, 16)); mx1 = fmaxf(mx1, __shfl_xor(mx1, 32));
        mn1 = fminf(mn1, __shfl_xor(mn1, 16)); mn1 = fminf(mn1, __shfl_xor(mn1, 32));
        if (quad == 0) {
            psum[(size_t)bx * 256 + col] = s;
            psq[(size_t)bx * 256 + col] = q2;
            size_t p0 = (size_t)(bx * 2) * 256 + col;
            size_t p1 = (size_t)(bx * 2 + 1) * 256 + col;
            ymax[p0] = mx0; ymin[p0] = mn0;
            ymax[p1] = mx1; ymin[p1] = mn1;
        }
    }
}

// ---------------- stats reduction: 64 blocks x 64 rows (coalesced), then 1-block finish ----------------
__global__ __launch_bounds__(256) void reduce1_k(const float* __restrict__ psum, const float* __restrict__ psq,
                                                 float* __restrict__ ps2, float* __restrict__ pq2) {
    int j = blockIdx.x, t = threadIdx.x;
    float s = 0.f, q = 0.f;
    #pragma unroll 4
    for (int kk = 0; kk < 64; kk++) {
        size_t r = (size_t)(j * 64 + kk) * 256 + t;
        s += psum[r]; q += psq[r];
    }
    ps2[j * 256 + t] = s;
    pq2[j * 256 + t] = q;
}

__global__ __launch_bounds__(256) void reduce2_k(const float* __restrict__ ps2, const float* __restrict__ pq2,
                                                 const float* __restrict__ gamma, const float* __restrict__ beta,
                                                 float* __restrict__ ab) {
    int c = threadIdx.x;
    float S = 0.f, Q = 0.f;
    for (int j = 0; j < 64; j++) {
        S += ps2[j * 256 + c];
        Q += pq2[j * 256 + c];
    }
    float mu = S * INV_N;
    float var = Q * INV_N - mu * mu;
    float a = gamma[c] * rsqrtf(var + 1e-5f);
    ab[c] = a;
    ab[256 + c] = beta[c] - mu * a;
}

// ---------------- final: relu(a*(a>=0?max:min)+b), transpose -> (B,O,N) ----------------
__global__ __launch_bounds__(256) void final_k(const float* __restrict__ ymax, const float* __restrict__ ymin,
                                               const float* __restrict__ ab, float* __restrict__ out) {
    __shared__ float sm[32 * 33];
    int b = blockIdx.z;
    int n0 = blockIdx.x * 32, o0 = blockIdx.y * 32;
    int t = threadIdx.x, x = t & 31, y = t >> 5;
    #pragma unroll
    for (int rr = 0; rr < 4; rr++) {
        int n = n0 + y + rr * 8;
        int o = o0 + x;
        float a = ab[o], bb = ab[256 + o];
        size_t p = (size_t)(b * NPTS + n) * 256 + o;
        float v = (a >= 0.f) ? ymax[p] : ymin[p];
        sm[(y + rr * 8) * 33 + x] = fmaxf(fmaf(v, a, bb), 0.f);
    }
    __syncthreads();
    #pragma unroll
    for (int rr = 0; rr < 4; rr++)
        out[((size_t)(b * 256 + o0 + y + rr * 8)) * NPTS + n0 + x] = sm[x * 33 + (y + rr * 8)];
}

extern "C" void kernel_launch(void* const* d_in, const int* in_sizes, int n_in,
                              void* d_out, int out_size, void* d_ws, size_t ws_size,
                              hipStream_t stream) {
    const float* xyz    = (const float*)d_in[0];
    const float* feat   = (const float*)d_in[1];
    const float* rot    = (const float*)d_in[2];
    const float* W1     = (const float*)d_in[3];
    const float* gamma1 = (const float*)d_in[4];
    const float* beta1  = (const float*)d_in[5];
    const float* W2     = (const float*)d_in[6];
    const float* gamma2 = (const float*)d_in[7];
    const float* beta2  = (const float*)d_in[8];
    float* out = (float*)d_out;

    char* ws = (char*)d_ws;
    u16*   featT = (u16*)(ws + 0);           //  4,194,304
    int*   idxp  = (int*)(ws + 4194304);     //  1,048,576
    u16*   gxyz  = (u16*)(ws + 5242880);     //  2,097,152
    u16*   Wp1   = (u16*)(ws + 7340032);     //    147,456
    u16*   Wp2   = (u16*)(ws + 7487488);     //    131,072
    float* ab1   = (float*)(ws + 7618560);   //      2,048
    float* ab2   = (float*)(ws + 7620608);   //      2,048
    float* Sacc  = (float*)(ws + 7753728);   //      1,024  (contiguous with Qacc/Xacc for memset)
    float* Qacc  = (float*)(ws + 7754752);   //      1,024
    float* Xacc  = (float*)(ws + 7755776);   //      1,024
    float* xst64 = (float*)(ws + 7756800);   //      4,096  (64 x 9 used)
    float* hpart = (float*)(ws + 7760896);   //  2,097,152  (64 x 8192 f32)
    float* psum  = (float*)(ws + 9858048);   //  4,194,304
    float* psq   = (float*)(ws + 14052352);  //  4,194,304
    float* ymax  = (float*)(ws + 18246656);  //  8,388,608
    float* ymin  = (float*)(ws + 26635264);  //  8,388,608
    const size_t NEED = 35023872ull;

    // stage-2 reduction scratch (borrowed dead regions):
    //  - stats1 reduce (fallback) runs before pass 2 writes ymin -> borrow ymin
    //  - stats2 reduce runs after gxyz last use -> borrow gxyz
    float* r1s = (float*)(ws + 26635264);
    float* r1q = r1s + 16384;
    float* r2s = (float*)(ws + 5242880);
    float* r2q = r2s + 16384;

    prep_k<<<256, 256, 0, stream>>>(W1, W2, Wp1, Wp2);
    query_k<<<2048, 256, 0, stream>>>(xyz, rot, idxp);
    featT_k<<<dim3(64, 8, 4), 256, 0, stream>>>(feat, featT);
    gxyz_k<<<1024, 256, 0, stream>>>(xyz, rot, idxp, gxyz);

    if (ws_size >= NEED) {
        // stats1 via Gram decomposition over the 8192 unique gathered rows (no y1 materialization)
        hipMemsetAsync(Sacc, 0, 3 * 1024, stream);   // Sacc,Qacc,Xacc
        hist_k<<<64, 256, 0, stream>>>(idxp, gxyz, hpart, xst64);
        zgemm_k<<<NROW / 64, 256, 0, stream>>>(featT, Wp1, hpart, Sacc, Qacc, Xacc);
        ab1_k<<<1, 256, 0, stream>>>(Sacc, Qacc, Xacc, xst64, Wp1, gamma1, beta1, ab1);
        // single heavy pass: GEMM1 -> norm1 (K-halved y1s) -> GEMM2 -> stats2 + max/min
        fused_k<1><<<NBLK, 256, 0, stream>>>(featT, gxyz, idxp, Wp1, Wp2, ab1, psum, psq, ymax, ymin);
        reduce1_k<<<64, 256, 0, stream>>>(psum, psq, r2s, r2q);
        reduce2_k<<<1, 256, 0, stream>>>(r2s, r2q, gamma2, beta2, ab2);
    } else {
        // fallback: recompute GEMM1 in pass 2 (proven path)
        fused_k<0><<<NBLK, 256, 0, stream>>>(featT, gxyz, idxp, Wp1, Wp2, ab1, psum, psq, ymax, ymin);
        reduce1_k<<<64, 256, 0, stream>>>(psum, psq, r1s, r1q);
        reduce2_k<<<1, 256, 0, stream>>>(r1s, r1q, gamma1, beta1, ab1);
        fused_k<1><<<NBLK, 256, 0, stream>>>(featT, gxyz, idxp, Wp1, Wp2, ab1, psum, psq, ymax, ymin);
        reduce1_k<<<64, 256, 0, stream>>>(psum, psq, r2s, r2q);
        reduce2_k<<<1, 256, 0, stream>>>(r2s, r2q, gamma2, beta2, ab2);
    }
    final_k<<<dim3(64, 8, 4), 256, 0, stream>>>(ymax, ymin, ab2, out);
}